// Round 5
// baseline (493.792 us; speedup 1.0000x reference)
//
#include <hip/hip_runtime.h>
#include <hip/hip_bf16.h>
#include <cstdint>
#include <cmath>

typedef __attribute__((ext_vector_type(4))) float f32x4;
typedef __attribute__((ext_vector_type(8))) short bf16x8;

#define BAR()   __builtin_amdgcn_s_barrier()
#define PRIO1() __builtin_amdgcn_s_setprio(1)
#define PRIO0() __builtin_amdgcn_s_setprio(0)
#define WAITV4() asm volatile("s_waitcnt vmcnt(4)" ::: "memory")
#define WAITV3() asm volatile("s_waitcnt vmcnt(3)" ::: "memory")
#define WAITV0() asm volatile("s_waitcnt vmcnt(0)" ::: "memory")
#define MM(a,b,c) __builtin_amdgcn_mfma_f32_16x16x32_bf16((a),(b),(c),0,0,0)

__device__ __forceinline__ void gl_lds16(const __hip_bfloat16* g, char* l) {
    __builtin_amdgcn_global_load_lds(
        (const __attribute__((address_space(1))) void*)g,
        (__attribute__((address_space(3))) void*)l, 16, 0, 0);
}
__device__ __forceinline__ void store_c(float* C, size_t i, float v) { C[i] = v; }
__device__ __forceinline__ void store_c(__hip_bfloat16* C, size_t i, float v) { C[i] = __float2bfloat16(v); }

// ---------------------------------------------------------------------------
// gemm256: 256x256 tile, BK=32, 8 waves, 3-buffer 96KB LDS (1 block/CU).
// R3/R4-proven control kernel (MODE0 dense only).
// ---------------------------------------------------------------------------
#define STAGEA(nb, kt) do{ gl_lds16(Asrc + (kt),                        lds + (nb)         + wb); \
                           gl_lds16(Asrc + (size_t)128 * lda + (kt),    lds + (nb) +  8192 + wb);}while(0)
#define STAGEB(nb, kt) do{ gl_lds16(Bsrc + (kt),                        lds + (nb) + 16384 + wb); \
                           gl_lds16(Bsrc + (size_t)128 * ldb + (kt),    lds + (nb) + 24576 + wb);}while(0)

template<typename CT>
__global__ __launch_bounds__(512, 2)
void gemm256(const __hip_bfloat16* __restrict__ A, const __hip_bfloat16* __restrict__ B,
             CT* __restrict__ C, int K, int lda, int ldb, int ldc, int nbx,
             float alpha, size_t sA, size_t sB, size_t sC)
{
    __shared__ __align__(1024) char lds[98304];

    // bijective XCD-aware swizzle (m204)
    const int nwg = gridDim.x;
    const int q8 = nwg >> 3, r8 = nwg & 7;
    const int xcd = blockIdx.x & 7, blk = blockIdx.x >> 3;
    const int wg = (xcd < r8 ? xcd * (q8 + 1) : r8 * (q8 + 1) + (xcd - r8) * q8) + blk;
    const int bm0 = (wg / nbx) * 256, bn0 = (wg % nbx) * 256;

    A += sA * blockIdx.y; B += sB * blockIdx.y; C += sC * blockIdx.y;

    const int tid  = threadIdx.x;
    const int lane = tid & 63;
    const int w    = tid >> 6;
    const int wb   = w * 1024;

    const int rb   = (lane & 15) * 64 + (lane >> 4) * 16;
    const int rswz = rb ^ (((rb >> 9) & 1) << 5);
    const int srA  = (w >> 2) * 8;
    const int srB  = (w & 3) * 4;

    const int q0 = tid * 16;
    const int uq = q0 ^ (((q0 >> 9) & 1) << 5);
    const int r0 = ((q0 >> 10) << 4) | ((uq >> 6) & 15);
    const int c0 = (uq & 63) >> 1;
    const __hip_bfloat16* Asrc = A + (size_t)(bm0 + r0) * lda + c0;
    const __hip_bfloat16* Bsrc = B + (size_t)(bn0 + r0) * ldb + c0;

    f32x4 acc[8][4] = {};
    bf16x8 af[4], bf[4];

    const int nt = K >> 5;

    STAGEA(0, 0); STAGEB(0, 0);
    if (nt > 1) { STAGEA(32768, 32); STAGEB(32768, 32); }

    for (int t = 0; t < nt; ++t) {
        if (t + 1 < nt) WAITV4(); else WAITV0();
        BAR();
        const char* dA = lds + (t % 3) * 32768;
        const char* dB = dA + 16384;
        const int  nbo = ((t + 2) % 3) * 32768;
        const bool pf  = (t + 2 < nt);
        const int  kt  = (t + 2) << 5;

#pragma unroll
        for (int i = 0; i < 4; ++i) af[i] = *(const bf16x8*)(dA + ((srA + i) << 10) + rswz);
#pragma unroll
        for (int i = 0; i < 4; ++i) bf[i] = *(const bf16x8*)(dB + ((srB + i) << 10) + rswz);
        if (pf) STAGEA(nbo, kt);
        BAR();
        PRIO1();
#pragma unroll
        for (int mi = 0; mi < 4; ++mi)
#pragma unroll
            for (int ni = 0; ni < 4; ++ni)
                acc[mi][ni] = MM(af[mi], bf[ni], acc[mi][ni]);
        PRIO0();

#pragma unroll
        for (int i = 0; i < 4; ++i) af[i] = *(const bf16x8*)(dA + ((srA + 4 + i) << 10) + rswz);
        if (pf) STAGEB(nbo, kt);
        BAR();
        PRIO1();
#pragma unroll
        for (int mi = 0; mi < 4; ++mi)
#pragma unroll
            for (int ni = 0; ni < 4; ++ni)
                acc[4 + mi][ni] = MM(af[mi], bf[ni], acc[4 + mi][ni]);
        PRIO0();
    }

    const int cr = (lane >> 4) * 4, cc = lane & 15;
    const int wrow = bm0 + (w >> 2) * 128, wcol = bn0 + (w & 3) * 64;
#pragma unroll
    for (int mi = 0; mi < 8; ++mi)
#pragma unroll
        for (int ni = 0; ni < 4; ++ni) {
            const int row = wrow + mi * 16 + cr;
            const int col = wcol + ni * 16 + cc;
#pragma unroll
            for (int j = 0; j < 4; ++j)
                store_c(C, (size_t)(row + j) * ldc + col, acc[mi][ni][j] * alpha);
        }
}

// ---------------------------------------------------------------------------
// gemm128: 128x256 tile, BK=32, 8 waves (2Mx4N, wave tile 64x64), 3-buffer
// 72KB LDS -> 2 blocks/CU (cross-block latency hiding, m114/m97 mechanism).
// Same swizzle + 2-tile-deep prefetch + counted vmcnt(3) ledger as gemm256.
// Per tile: 1 barrier, 8 ds_read_b128, 3 global_load_lds, 16 MFMA per wave.
// MODE 0: dense, bijective XCD swizzle. MODE 1: causal S triangular blocks
// (grid 72/batch). MODE 2: PV, kend=bm0+128, diagonal-shifted mapping.
// ---------------------------------------------------------------------------
#define STG128(buf, kt) do{ \
    gl_lds16(Asrc + (kt),  lds + (buf) * 24576 +         w * 1024); \
    gl_lds16(Bsrc0 + (kt), lds + (buf) * 24576 +  8192 + w * 1024); \
    gl_lds16(Bsrc1 + (kt), lds + (buf) * 24576 + 16384 + w * 1024); }while(0)

template<typename CT, int MODE>
__global__ __launch_bounds__(512, 4)
void gemm128(const __hip_bfloat16* __restrict__ A, const __hip_bfloat16* __restrict__ B,
             CT* __restrict__ C, int K, int lda, int ldb, int ldc, int nbx,
             float alpha, size_t sA, size_t sB, size_t sC)
{
    __shared__ __align__(1024) char lds[73728];

    int bm0, bn0;
    if (MODE == 1) {
        int g = blockIdx.x, r = 0;
        while (g >= (r >> 1) + 1) { g -= (r >> 1) + 1; ++r; }   // <=16 iters
        bm0 = r << 7; bn0 = g << 8;
    } else if (MODE == 2) {
        const int g = blockIdx.x;
        const int nby = gridDim.x / nbx;
        const int bx = g % nbx;
        const int by = (g / nbx + bx) % nby;
        bm0 = by << 7; bn0 = bx << 8;
    } else {
        const int nwg = gridDim.x;
        const int q8 = nwg >> 3, r8 = nwg & 7;
        const int xcd = blockIdx.x & 7, blk = blockIdx.x >> 3;
        const int wg = (xcd < r8 ? xcd * (q8 + 1) : r8 * (q8 + 1) + (xcd - r8) * q8) + blk;
        bm0 = (wg / nbx) << 7; bn0 = (wg % nbx) << 8;
    }

    A += sA * blockIdx.y; B += sB * blockIdx.y; C += sC * blockIdx.y;

    const int tid  = threadIdx.x;
    const int lane = tid & 63;
    const int w    = tid >> 6;

    // ds_read: per-lane swizzled inner offset; subtile bases
    const int rb   = (lane & 15) * 64 + (lane >> 4) * 16;
    const int rswz = rb ^ (((rb >> 9) & 1) << 5);
    const int stA  = (w >> 2) * 4;      // + mi -> A subtile 0..7
    const int stB  = (w & 3) * 4;       // + ni -> B subtile 0..15

    // staging sources (inverse-swizzled): A region 8KB (1 load), B 16KB (2)
    const int qA  = tid * 16;
    const int uqA = qA ^ (((qA >> 9) & 1) << 5);
    const int rA  = ((qA >> 10) << 4) | ((uqA >> 6) & 15);
    const int cA  = (uqA & 63) >> 1;
    const int qB1  = 8192 + tid * 16;
    const int uqB1 = qB1 ^ (((qB1 >> 9) & 1) << 5);
    const int rB1  = ((qB1 >> 10) << 4) | ((uqB1 >> 6) & 15);
    const int cB1  = (uqB1 & 63) >> 1;
    const __hip_bfloat16* Asrc  = A + (size_t)(bm0 + rA) * lda + cA;
    const __hip_bfloat16* Bsrc0 = B + (size_t)(bn0 + rA) * ldb + cA;
    const __hip_bfloat16* Bsrc1 = B + (size_t)(bn0 + rB1) * ldb + cB1;

    f32x4 acc[4][4] = {};
    bf16x8 af[4], bf[4];

    const int klim = bm0 + 128;
    const int kend = (MODE == 2) ? (K < klim ? K : klim) : K;
    const int nt   = kend >> 5;

    STG128(0, 0);
    if (nt > 1) STG128(1, 32);

    for (int t = 0; t < nt; ++t) {
        if (t + 1 < nt) WAITV3(); else WAITV0();
        BAR();
        const char* dA = lds + (t % 3) * 24576;
        const char* dB = dA + 8192;
#pragma unroll
        for (int i = 0; i < 4; ++i) af[i] = *(const bf16x8*)(dA + ((stA + i) << 10) + rswz);
#pragma unroll
        for (int i = 0; i < 4; ++i) bf[i] = *(const bf16x8*)(dB + ((stB + i) << 10) + rswz);
        if (t + 2 < nt) STG128((t + 2) % 3, (t + 2) << 5);
        PRIO1();
#pragma unroll
        for (int mi = 0; mi < 4; ++mi)
#pragma unroll
            for (int ni = 0; ni < 4; ++ni)
                acc[mi][ni] = MM(af[mi], bf[ni], acc[mi][ni]);
        PRIO0();
    }

    // epilogue: C/D layout col=lane&15, row=(lane>>4)*4+j (m89/m91)
    const int cr = (lane >> 4) * 4, cc = lane & 15;
    const int wrow = bm0 + (w >> 2) * 64, wcol = bn0 + (w & 3) * 64;
#pragma unroll
    for (int mi = 0; mi < 4; ++mi)
#pragma unroll
        for (int ni = 0; ni < 4; ++ni) {
            const int row = wrow + mi * 16 + cr;
            const int col = wcol + ni * 16 + cc;
#pragma unroll
            for (int j = 0; j < 4; ++j)
                store_c(C, (size_t)(row + j) * ldc + col, acc[mi][ni][j] * alpha);
        }
}

// ---------------------------------------------------------------------------
__global__ void f32_to_bf16_vec(const float* __restrict__ in,
                                __hip_bfloat16* __restrict__ out, int n4)
{
    int i = blockIdx.x * 256 + threadIdx.x;
    if (i >= n4) return;
    float4 v = ((const float4*)in)[i];
    union { ushort4 u; __hip_bfloat16 h[4]; } o;
    o.h[0] = __float2bfloat16(v.x);
    o.h[1] = __float2bfloat16(v.y);
    o.h[2] = __float2bfloat16(v.z);
    o.h[3] = __float2bfloat16(v.w);
    ((ushort4*)out)[i] = o.u;
}

__global__ void conv_w4(const float* __restrict__ w0, const float* __restrict__ w1,
                        const float* __restrict__ w2, const float* __restrict__ w3,
                        __hip_bfloat16* o0, __hip_bfloat16* o1,
                        __hip_bfloat16* o2, __hip_bfloat16* o3, int n4)
{
    int i = blockIdx.x * 256 + threadIdx.x;
    if (i >= n4) return;
    const float* src; __hip_bfloat16* dst;
    switch (blockIdx.y) {
        case 0: src = w0; dst = o0; break;
        case 1: src = w1; dst = o1; break;
        case 2: src = w2; dst = o2; break;
        default: src = w3; dst = o3; break;
    }
    float4 v = ((const float4*)src)[i];
    union { ushort4 u; __hip_bfloat16 h[4]; } o;
    o.h[0] = __float2bfloat16(v.x);
    o.h[1] = __float2bfloat16(v.y);
    o.h[2] = __float2bfloat16(v.z);
    o.h[3] = __float2bfloat16(v.w);
    ((ushort4*)dst)[i] = o.u;
}

__global__ void rope_table(const int* __restrict__ pos, float2* __restrict__ tab, int N)
{
    int i = blockIdx.x * 256 + threadIdx.x;
    if (i >= N * 64) return;
    int n = i >> 6, j = i & 63;
    float p = (float)pos[n];
    float ang = p * powf(10000.f, -(float)j * (1.0f / 64.0f));
    tab[i] = make_float2(cosf(ang), sinf(ang));
}

__global__ void rope_apply2(__hip_bfloat16* __restrict__ Q, __hip_bfloat16* __restrict__ K,
                            const float2* __restrict__ tab)
{
    int i = blockIdx.x * 256 + threadIdx.x;     // 8192 rows x 256 chunks
    __hip_bfloat16* T = blockIdx.y ? K : Q;
    int r  = i >> 8;
    int cb = (i & 255) << 3;
    int n  = r & 2047;
    int j0 = (cb >> 1) & 63;
    union { bf16x8 v; __hip_bfloat162 h[4]; } u;
    __hip_bfloat16* p = T + ((size_t)r << 11) + cb;
    u.v = *(const bf16x8*)p;
#pragma unroll
    for (int k = 0; k < 4; ++k) {
        float2 cs = tab[(n << 6) + j0 + k];
        float x1 = __bfloat162float(u.h[k].x);
        float x2 = __bfloat162float(u.h[k].y);
        u.h[k].x = __float2bfloat16(cs.x * x1 - cs.y * x2);
        u.h[k].y = __float2bfloat16(cs.y * x1 + cs.x * x2);
    }
    *(bf16x8*)p = u.v;
}

// ---------------------------------------------------------------------------
__global__ void softmax_causal_ip(float* __restrict__ S, int N)
{
    const int q = blockIdx.x;
    float* srow = S + ((size_t)blockIdx.y * N + q) * N;
    __shared__ float buf[2048];
    __shared__ float red[8];
    const int tid = threadIdx.x;

    float4* b4 = (float4*)buf;
    const float4* s4 = (const float4*)srow;
    for (int i = tid; i < N / 4; i += 256) b4[i] = s4[i];
    __syncthreads();

    float m = -1e30f;
    for (int j = tid; j <= q; j += 256) m = fmaxf(m, buf[j]);
#pragma unroll
    for (int o = 32; o > 0; o >>= 1) m = fmaxf(m, __shfl_xor(m, o));
    if ((tid & 63) == 0) red[tid >> 6] = m;
    __syncthreads();
    m = fmaxf(fmaxf(red[0], red[1]), fmaxf(red[2], red[3]));

    float sum = 0.f;
    for (int j = tid; j <= q; j += 256) { float e = __expf(buf[j] - m); buf[j] = e; sum += e; }
#pragma unroll
    for (int o = 32; o > 0; o >>= 1) sum += __shfl_xor(sum, o);
    if ((tid & 63) == 0) red[4 + (tid >> 6)] = sum;
    __syncthreads();
    const float inv = 1.f / (red[4] + red[5] + red[6] + red[7]);

    __hip_bfloat162* p2 = (__hip_bfloat162*)srow;
    for (int i = tid; i < N / 2; i += 256) {
        int j0 = i * 2;
        __hip_bfloat162 h;
        h.x = __float2bfloat16(j0     <= q ? buf[j0]     * inv : 0.f);
        h.y = __float2bfloat16(j0 + 1 <= q ? buf[j0 + 1] * inv : 0.f);
        p2[i] = h;
    }
}

__global__ void transpose_bf16(const __hip_bfloat16* __restrict__ V,
                               __hip_bfloat16* __restrict__ Vt, int N)
{
    __shared__ __hip_bfloat16 tile[32][33];
    const size_t bo = (size_t)blockIdx.z * N * N;
    const int k0 = blockIdx.x * 32, d0 = blockIdx.y * 32;
    const int tx = threadIdx.x, ty = threadIdx.y;   // 32 x 8
#pragma unroll
    for (int j = 0; j < 4; ++j)
        tile[ty + 8 * j][tx] = V[bo + (size_t)(k0 + ty + 8 * j) * N + d0 + tx];
    __syncthreads();
#pragma unroll
    for (int j = 0; j < 4; ++j)
        Vt[bo + (size_t)(d0 + ty + 8 * j) * N + k0 + tx] = tile[tx][ty + 8 * j];
}

// ---------------------------------------------------------------------------
extern "C" void kernel_launch(void* const* d_in, const int* in_sizes, int n_in,
                              void* d_out, int out_size, void* d_ws, size_t ws_size,
                              hipStream_t stream)
{
    const float* x  = (const float*)d_in[0];
    const int* pos  = (const int*)d_in[1];
    const float* wq = (const float*)d_in[2];
    const float* wk = (const float*)d_in[3];
    const float* wv = (const float*)d_in[4];
    const float* wo = (const float*)d_in[5];
    float* out = (float*)d_out;

    const int B = 4, N = 2048, D = 2048;
    const int M = B * N;                      // 8192
    const size_t MB = 1ull << 20;
    if (ws_size < 192 * MB) return;

    char* w = (char*)d_ws;
    __hip_bfloat16* Qb  = (__hip_bfloat16*)(w + 0 * MB);
    __hip_bfloat16* Kb  = (__hip_bfloat16*)(w + 32 * MB);
    __hip_bfloat16* Vb  = (__hip_bfloat16*)(w + 64 * MB);
    __hip_bfloat16* wqb = (__hip_bfloat16*)(w + 96 * MB);
    __hip_bfloat16* wkb = (__hip_bfloat16*)(w + 104 * MB);
    __hip_bfloat16* wvb = (__hip_bfloat16*)(w + 112 * MB);
    __hip_bfloat16* wob = (__hip_bfloat16*)(w + 120 * MB);
    __hip_bfloat16* xb  = (__hip_bfloat16*)(w + 128 * MB);  // dead after projections
    __hip_bfloat16* Vt  = xb;                                // alias
    __hip_bfloat16* AO  = (__hip_bfloat16*)(w + 160 * MB);
    float2*         tab = (float2*)(w + 190 * MB);           // 1 MiB

    float* Sal = (float*)d_out;              // S for all 4 batches = 64MB = d_out

    // 1. convert to bf16 (x + 4 weights), RoPE table
    f32_to_bf16_vec<<<(M * D / 4 + 255) / 256, 256, 0, stream>>>(x, xb, M * D / 4);
    conv_w4<<<dim3((D * D / 4 + 255) / 256, 4), 256, 0, stream>>>(
        wq, wk, wv, wo, wqb, wkb, wvb, wob, D * D / 4);
    rope_table<<<(N * 64 + 255) / 256, 256, 0, stream>>>(pos, tab, N);

    // 2. projections — A/B probe: Q,K on gemm128 (512 wgs, 2/CU); V on gemm256
    gemm128<__hip_bfloat16, 0><<<dim3((D / 256) * (M / 128)), 512, 0, stream>>>(
        xb, wqb, Qb, D, D, D, D, D / 256, 1.f, 0, 0, 0);
    gemm128<__hip_bfloat16, 0><<<dim3((D / 256) * (M / 128)), 512, 0, stream>>>(
        xb, wkb, Kb, D, D, D, D, D / 256, 1.f, 0, 0, 0);
    gemm256<__hip_bfloat16><<<dim3((D / 256) * (M / 256)), 512, 0, stream>>>(
        xb, wvb, Vb, D, D, D, D, D / 256, 1.f, 0, 0, 0);

    // 3. RoPE on Q and K (one dispatch)
    rope_apply2<<<dim3(M * 256 / 256, 2), 256, 0, stream>>>(Qb, Kb, tab);

    // 4. V transpose (Vt aliases dead xb)
    transpose_bf16<<<dim3(N / 32, N / 32, B), dim3(32, 8), 0, stream>>>(Vb, Vt, N);

    // 5. attention
    const float scale = 1.0f / sqrtf((float)D);
    // S: triangular 128-row blocks, 72/batch
    gemm128<float, 1><<<dim3(72, B), 512, 0, stream>>>(
        Qb, Kb, Sal, D, D, D, N, N / 256, scale, (size_t)N * D, (size_t)N * D, (size_t)N * N);
    softmax_causal_ip<<<dim3(N, B), 256, 0, stream>>>(Sal, N);
    // PV: 16x8 = 128 blocks/batch, diagonal-shifted, kend = bm0+128
    gemm128<__hip_bfloat16, 2><<<dim3((N / 128) * (N / 256), B), 512, 0, stream>>>(
        (const __hip_bfloat16*)Sal, Vt, AO, N, 2 * N, D, D, N / 256, 1.f,
        (size_t)2 * N * N, (size_t)N * D, (size_t)N * D);

    // 6. output projection (control: gemm256)
    gemm256<float><<<dim3((D / 256) * (M / 256)), 512, 0, stream>>>(
        AO, wob, out, D, D, D, D, D / 256, 1.f, 0, 0, 0);
}